// Round 2
// baseline (1498.827 us; speedup 1.0000x reference)
//
#include <hip/hip_runtime.h>
#include <stdint.h>
#include <math.h>

#define LRES 8192
#define KNB  48
#define APAD 49     // padded edge stride for A_T (49%32=17, conflict-free)
#define KMAIN 288   // 416 - 128 (h_i block folded into per-residue bias)

// ---------------- prep: transpose weights into workspace ----------------
__global__ void prep_kernel(const float* __restrict__ We, const float* __restrict__ Wproj,
                            float* __restrict__ WT, float* __restrict__ WPT) {
  int t = blockIdx.x * blockDim.x + threadIdx.x;
  if (t < 128 * 416) { int n = t / 416, k = t % 416; WT[k * 128 + n] = We[t]; }
  if (t < 128 * 128) { int m = t >> 7, n = t & 127; WPT[n * 128 + m] = Wproj[t]; }
}

// ---------------- knn: exact top-48 ordered by float64 (D, idx) ----------------
// Matches a float64 numpy golden reference: dx,dy,dz exact in double (fp32 inputs),
// d2 summed in double, D = sqrt(d2 + 1e-6) in double. Lexicographic (D, idx).
__global__ __launch_bounds__(256) void knn_kernel(const float* __restrict__ X,
                                                  int* __restrict__ out_idx,
                                                  float* __restrict__ out_D) {
  __shared__ float Dbuf[LRES];        // fp32 D for binning only
  __shared__ unsigned hist[1024];
  __shared__ unsigned psum[256];
  __shared__ double candD[256];
  __shared__ int candJ[256];
  __shared__ unsigned cnt;
  __shared__ int bstar_s;
  const int i = blockIdx.x;
  const int tid = threadIdx.x;
  const float xi = X[i * 3 + 0], yi = X[i * 3 + 1], zi = X[i * 3 + 2];
  for (int b = tid; b < 1024; b += 256) hist[b] = 0u;
  if (tid == 0) cnt = 0u;
  __syncthreads();
  // pass 1: fp32 distances -> histogram (binning only; fp64 slack handled below)
  for (int j = tid; j < LRES; j += 256) {
    float dx = X[j * 3 + 0] - xi;
    float dy = X[j * 3 + 1] - yi;
    float dz = X[j * 3 + 2] - zi;
    float D = sqrtf(dx * dx + dy * dy + dz * dz + 1e-6f);
    Dbuf[j] = D;
    int b = (int)(D * 4.0f); if (b > 1023) b = 1023;
    atomicAdd(&hist[b], 1u);
  }
  __syncthreads();
  unsigned s4 = hist[tid * 4 + 0] + hist[tid * 4 + 1] + hist[tid * 4 + 2] + hist[tid * 4 + 3];
  psum[tid] = s4;
  __syncthreads();
  if (tid == 0) {
    unsigned run = 0; int g = 0;
    while (g < 255 && run + psum[g] < KNB) { run += psum[g]; ++g; }
    int b = g * 4;
    while (b < g * 4 + 3 && run + hist[b] < KNB) { run += hist[b]; ++b; }
    bstar_s = b;  // cumulative fp32-binned count through b is >= KNB
  }
  __syncthreads();
  int bthr = bstar_s + 1; if (bthr > 1023) bthr = 1023;  // +1 bin slack covers fp32 binning error
  // pass 2: collect candidates, compute exact fp64 key
  const double xid = (double)xi, yid = (double)yi, zid = (double)zi;
  for (int j = tid; j < LRES; j += 256) {
    float D = Dbuf[j];
    int b = (int)(D * 4.0f); if (b > 1023) b = 1023;
    if (b <= bthr) {
      unsigned p = atomicAdd(&cnt, 1u);
      if (p < 256u) {
        double dx = (double)X[j * 3 + 0] - xid;
        double dy = (double)X[j * 3 + 1] - yid;
        double dz = (double)X[j * 3 + 2] - zid;
        candD[p] = sqrt(dx * dx + dy * dy + dz * dz + 1e-6);
        candJ[p] = j;
      }
    }
  }
  __syncthreads();
  unsigned n = cnt;  // >= KNB by construction; typically ~60-90, cap 256
  if (tid >= (int)n) { candD[tid] = INFINITY; candJ[tid] = 0x7FFFFFFF; }
  __syncthreads();
  // bitonic sort 256 (D,idx) pairs ascending lexicographic == jax top_k order
  for (unsigned size = 2; size <= 256; size <<= 1) {
    for (unsigned stride = size >> 1; stride > 0; stride >>= 1) {
      unsigned partner = (unsigned)tid ^ stride;
      if (partner > (unsigned)tid) {
        double da = candD[tid], db = candD[partner];
        int ja = candJ[tid], jb = candJ[partner];
        bool agtb = (da > db) || (da == db && ja > jb);
        bool asc = ((tid & size) == 0);
        if (agtb == asc) {
          candD[tid] = db; candJ[tid] = jb;
          candD[partner] = da; candJ[partner] = ja;
        }
      }
      __syncthreads();
    }
  }
  if (tid < KNB) {
    out_idx[(size_t)i * KNB + tid] = candJ[tid];
    out_D[(size_t)i * KNB + tid] = (float)candD[tid];
  }
}

// ---------------- edge kernel: features + GEMM(288) + LN + GEMM(128), one block per residue ----------------
__global__ __launch_bounds__(256) void edge_kernel(
    const float* __restrict__ X, const float* __restrict__ node_h,
    const float* __restrict__ f_node, const float* __restrict__ Wpos,
    const float* __restrict__ bpos, const float* __restrict__ ln_scale,
    const float* __restrict__ ln_bias, const float* __restrict__ bproj,
    const int* __restrict__ aatype, const int* __restrict__ residue_index,
    const int* __restrict__ ws_idx, const float* __restrict__ ws_D,
    const float* __restrict__ WT, const float* __restrict__ WPT,
    float* __restrict__ out) {
  __shared__ __align__(16) float AT[KMAIN][APAD];     // 56448 B, e_in^T (h_i block removed)
  __shared__ __align__(16) float Wlds[2][16][128];    // 16384 B, double-buffered weight chunks
  __shared__ float hbiasL[128];                       // We[:,160:288] @ h_i
  __shared__ float lnsL[128], lnbL[128], bprojL[128];

  // pool aliases inside Wlds (pre-GEMM phase / between-GEMM phase only)
  float* pool   = &Wlds[0][0][0];
  float* WposLp = pool;               // 1056 floats [16][66]
  float* bposLp = pool + 1056;        // 16
  float* geomLp = pool + 1072;        // 384  [48][8]
  float* DkLp   = pool + 1456;        // 48
  int*   jLp    = (int*)(pool + 1504);
  int*   pidxLp = (int*)(pool + 1552);
  int*   aaLp   = (int*)(pool + 1600);
  float* hiLp   = pool + 1648;        // 128
  float* hbPp   = pool + 1776;        // 256 [2][128]
  // post-GEMM1 aliases (GEMM1 done before these are written):
  float* redS1p = pool;               // 768 [48][16]
  float* redS2p = pool + 768;         // 768
  float* meanLp = pool + 1536;        // 48
  float* rstdLp = pool + 1584;        // 48

  const int i = blockIdx.x;
  const int tid = threadIdx.x;
  const int eg = tid & 15, ng = tid >> 4;
  const int eg3 = eg * 3, ng8 = ng * 8;

  // ---- P0: small loads + per-edge scalars ----
  if (tid < 128) {
    lnsL[tid] = ln_scale[tid];
    lnbL[tid] = ln_bias[tid];
    bprojL[tid] = bproj[tid];
    hiLp[tid] = node_h[(size_t)i * 128 + tid];
  }
  for (int t = tid; t < 1056; t += 256) WposLp[t] = Wpos[t];
  if (tid < 16) bposLp[tid] = bpos[tid];
  const float xi = X[i * 3 + 0], yi = X[i * 3 + 1], zi = X[i * 3 + 2];
  if (tid < KNB) {
    int e = tid;
    int j = ws_idx[(size_t)i * KNB + e];
    float Dk = ws_D[(size_t)i * KNB + e];
    jLp[e] = j; DkLp[e] = Dk;
    float xj = X[j * 3 + 0], yj = X[j * 3 + 1], zj = X[j * 3 + 2];
    float inv = 1.0f / (Dk + 1e-6f);
    geomLp[e * 8 + 0] = Dk / 10.0f;
    geomLp[e * 8 + 1] = 1.0f / (1.0f + Dk);
    geomLp[e * 8 + 2] = expf(-Dk);
    geomLp[e * 8 + 3] = sinf(Dk);
    geomLp[e * 8 + 4] = cosf(Dk);
    geomLp[e * 8 + 5] = (xj - xi) * inv;
    geomLp[e * 8 + 6] = (yj - yi) * inv;
    geomLp[e * 8 + 7] = (zj - zi) * inv;
    int off = residue_index[j] - residue_index[i] + 8;
    off = off < 0 ? 0 : (off > 15 ? 15 : off);
    pidxLp[e] = off;
    aaLp[e] = aatype[j];
  }
  __syncthreads();

  // ---- P1: rbf into AT rows 144..159 + gathers f_node[j] / node_h[j] ----
  for (int t = tid; t < KNB * 16; t += 256) {
    int m = t & 15, e = t >> 4;
    float z = (DkLp[e] - (2.0f + (float)m * (20.0f / 15.0f))) * 0.8f;
    AT[144 + m][e] = expf(-z * z);
  }
  for (int t = tid; t < KNB * 128; t += 256) {
    int e = t >> 7, cc = t & 127;
    size_t j = (size_t)jLp[e];
    AT[cc][e] = f_node[j * 128 + cc];
    AT[160 + cc][e] = node_h[j * 128 + cc];
  }
  __syncthreads();

  // ---- P2: e_pos into AT rows 128..143 + h_i bias partials ----
  for (int t = tid; t < KNB * 16; t += 256) {
    int p = t & 15, e = t >> 4;
    const float* wp = WposLp + p * 66;
    float s = bposLp[p] + wp[pidxLp[e]] + wp[40 + aaLp[e]];
#pragma unroll
    for (int m = 0; m < 16; ++m) s = fmaf(AT[144 + m][e], wp[16 + m], s);
#pragma unroll
    for (int g = 0; g < 8; ++g) s = fmaf(geomLp[e * 8 + g], wp[32 + g], s);
    AT[128 + p][e] = s;
  }
  {
    int n = tid & 127, half = tid >> 7;
    float p = 0.f;
#pragma unroll 8
    for (int c0 = 0; c0 < 64; ++c0) {
      int cc = half * 64 + c0;
      p = fmaf(WT[(size_t)(160 + cc) * 128 + n], hiLp[cc], p);
    }
    hbPp[half * 128 + n] = p;
  }
  __syncthreads();
  if (tid < 128) hbiasL[tid] = hbPp[tid] + hbPp[128 + tid];
  __syncthreads();

  // ---- GEMM1: e = A(48x288) * W(288x128), per-thread 3x8 tile ----
  const int f0 = tid, f1 = tid + 256;
  const int kl0 = f0 >> 5, c40 = f0 & 31;
  const int kl1 = f1 >> 5, c41 = f1 & 31;
  {
    float4* dst = (float4*)&Wlds[0][0][0];
    dst[f0] = *(const float4*)(WT + (size_t)kl0 * 128 + c40 * 4);
    dst[f1] = *(const float4*)(WT + (size_t)kl1 * 128 + c41 * 4);
  }
  __syncthreads();
  float acc[3][8];
#pragma unroll
  for (int u = 0; u < 3; ++u)
#pragma unroll
    for (int v = 0; v < 8; ++v) acc[u][v] = 0.f;

  for (int c = 0; c < 18; ++c) {
    float4 pf0, pf1;
    const bool hasNext = (c + 1 < 18);
    if (hasNext) {
      int base = ((c + 1) < 10) ? (c + 1) * 16 : (c + 1) * 16 + 128;  // skip h_i cols 160..287
      pf0 = *(const float4*)(WT + (size_t)(base + kl0) * 128 + c40 * 4);
      pf1 = *(const float4*)(WT + (size_t)(base + kl1) * 128 + c41 * 4);
    }
    float (*Wb)[128] = Wlds[c & 1];
#pragma unroll
    for (int kl = 0; kl < 16; ++kl) {
      const float* at = AT[c * 16 + kl];
      float a0 = at[eg3 + 0], a1 = at[eg3 + 1], a2 = at[eg3 + 2];
      const float* wr = &Wb[kl][ng8];
      float w[8];
      *(float4*)(w + 0) = *(const float4*)(wr + 0);
      *(float4*)(w + 4) = *(const float4*)(wr + 4);
#pragma unroll
      for (int v = 0; v < 8; ++v) {
        acc[0][v] = fmaf(a0, w[v], acc[0][v]);
        acc[1][v] = fmaf(a1, w[v], acc[1][v]);
        acc[2][v] = fmaf(a2, w[v], acc[2][v]);
      }
    }
    if (hasNext) {
      float4* dst = (float4*)&Wlds[(c + 1) & 1][0][0];
      dst[f0] = pf0; dst[f1] = pf1;
    }
    __syncthreads();
  }

  // ---- h_i bias + LayerNorm ----
#pragma unroll
  for (int u = 0; u < 3; ++u)
#pragma unroll
    for (int v = 0; v < 8; ++v) acc[u][v] += hbiasL[ng8 + v];
#pragma unroll
  for (int u = 0; u < 3; ++u) {
    float p1 = 0.f, p2 = 0.f;
#pragma unroll
    for (int v = 0; v < 8; ++v) { float e = acc[u][v]; p1 += e; p2 += e * e; }
    redS1p[(eg3 + u) * 16 + ng] = p1;
    redS2p[(eg3 + u) * 16 + ng] = p2;
  }
  __syncthreads();
  if (tid < KNB) {
    float m = 0.f, q = 0.f;
#pragma unroll
    for (int g = 0; g < 16; ++g) { m += redS1p[tid * 16 + g]; q += redS2p[tid * 16 + g]; }
    m *= (1.0f / 128.0f);
    float var = q * (1.0f / 128.0f) - m * m;
    meanLp[tid] = m;
    rstdLp[tid] = rsqrtf(var + 1e-5f);
  }
  __syncthreads();

  // ---- eln written transposed into AT rows 0..127 (A no longer needed) ----
  float* ET = &AT[0][0];
#pragma unroll
  for (int u = 0; u < 3; ++u) {
    int r = eg3 + u;
    float mm = meanLp[r], rs = rstdLp[r];
#pragma unroll
    for (int v = 0; v < 8; ++v) {
      int n = ng8 + v;
      float e = (acc[u][v] - mm) * rs * lnsL[n] + lnbL[n];
      ET[(size_t)n * APAD + r] = e;
    }
  }
  __syncthreads();

  // ---- GEMM2: out = eln(48x128) * WPT(128x128) + bproj ----
  {
    float4* dst = (float4*)&Wlds[0][0][0];
    dst[f0] = *(const float4*)(WPT + (size_t)kl0 * 128 + c40 * 4);
    dst[f1] = *(const float4*)(WPT + (size_t)kl1 * 128 + c41 * 4);
  }
  __syncthreads();
  float acc2[3][8];
#pragma unroll
  for (int u = 0; u < 3; ++u)
#pragma unroll
    for (int v = 0; v < 8; ++v) acc2[u][v] = 0.f;

  for (int c = 0; c < 8; ++c) {
    float4 pf0, pf1;
    const bool hasNext = (c + 1 < 8);
    if (hasNext) {
      int base = (c + 1) * 16;
      pf0 = *(const float4*)(WPT + (size_t)(base + kl0) * 128 + c40 * 4);
      pf1 = *(const float4*)(WPT + (size_t)(base + kl1) * 128 + c41 * 4);
    }
    float (*Wb)[128] = Wlds[c & 1];
#pragma unroll
    for (int kl = 0; kl < 16; ++kl) {
      const float* et = ET + (size_t)(c * 16 + kl) * APAD;
      float a0 = et[eg3 + 0], a1 = et[eg3 + 1], a2 = et[eg3 + 2];
      const float* wr = &Wb[kl][ng8];
      float w[8];
      *(float4*)(w + 0) = *(const float4*)(wr + 0);
      *(float4*)(w + 4) = *(const float4*)(wr + 4);
#pragma unroll
      for (int v = 0; v < 8; ++v) {
        acc2[0][v] = fmaf(a0, w[v], acc2[0][v]);
        acc2[1][v] = fmaf(a1, w[v], acc2[1][v]);
        acc2[2][v] = fmaf(a2, w[v], acc2[2][v]);
      }
    }
    if (hasNext) {
      float4* dst = (float4*)&Wlds[(c + 1) & 1][0][0];
      dst[f0] = pf0; dst[f1] = pf1;
    }
    __syncthreads();
  }

  // ---- store ----
#pragma unroll
  for (int u = 0; u < 3; ++u) {
    float* op = out + ((size_t)i * KNB + eg3 + u) * 128 + ng8;
    float4 o0, o1;
    o0.x = acc2[u][0] + bprojL[ng8 + 0];
    o0.y = acc2[u][1] + bprojL[ng8 + 1];
    o0.z = acc2[u][2] + bprojL[ng8 + 2];
    o0.w = acc2[u][3] + bprojL[ng8 + 3];
    o1.x = acc2[u][4] + bprojL[ng8 + 4];
    o1.y = acc2[u][5] + bprojL[ng8 + 5];
    o1.z = acc2[u][6] + bprojL[ng8 + 6];
    o1.w = acc2[u][7] + bprojL[ng8 + 7];
    *(float4*)(op + 0) = o0;
    *(float4*)(op + 4) = o1;
  }
}

extern "C" void kernel_launch(void* const* d_in, const int* in_sizes, int n_in,
                              void* d_out, int out_size, void* d_ws, size_t ws_size,
                              hipStream_t stream) {
  const float* X        = (const float*)d_in[0];
  const float* node_h   = (const float*)d_in[1];
  const float* f_node   = (const float*)d_in[2];
  const float* Wpos     = (const float*)d_in[3];
  const float* bpos     = (const float*)d_in[4];
  const float* We       = (const float*)d_in[5];
  const float* ln_scale = (const float*)d_in[6];
  const float* ln_bias  = (const float*)d_in[7];
  const float* Wproj    = (const float*)d_in[8];
  const float* bproj    = (const float*)d_in[9];
  const int*   aatype   = (const int*)d_in[10];
  const int*   residue_index = (const int*)d_in[11];
  float* out = (float*)d_out;

  char* ws = (char*)d_ws;
  int*   ws_idx = (int*)ws;                    // L*K ints      (1.5 MB)
  float* ws_D   = (float*)(ws + 1572864);      // L*K floats    (1.5 MB)
  float* WT     = (float*)(ws + 3145728);      // 416*128 float (213 KB)
  float* WPT    = (float*)(ws + 3358720);      // 128*128 float (64 KB)

  prep_kernel<<<208, 256, 0, stream>>>(We, Wproj, WT, WPT);
  knn_kernel<<<LRES, 256, 0, stream>>>(X, ws_idx, ws_D);
  edge_kernel<<<LRES, 256, 0, stream>>>(X, node_h, f_node, Wpos, bpos, ln_scale,
                                        ln_bias, bproj, aatype, residue_index,
                                        ws_idx, ws_D, WT, WPT, out);
}

// Round 3
// 498.778 us; speedup vs baseline: 3.0050x; 3.0050x over previous
//
#include <hip/hip_runtime.h>
#include <stdint.h>
#include <math.h>

#define LRES 8192
#define KNB  48
#define ASTR 296   // f16 row stride for A (148 words: only 2-way bank aliasing = free)

typedef _Float16 half_t;
typedef _Float16 half8 __attribute__((ext_vector_type(8)));
typedef float f4 __attribute__((ext_vector_type(4)));

// ---------------- prep: convert/reorder weights into workspace ----------------
// WeH [n=128][k'=288] f16 : k'<160 -> orig col k', k'>=160 -> orig col k'+128 (skip h_i block)
// WpH [n=128][k=128] f16  : Wproj as-is (row-major = n-major, k contiguous)
// Wh32 [cc=128][n=128] f32: We[:,160+cc] transposed (for fp32 h_i bias GEMV)
__global__ void prep_kernel(const float* __restrict__ We, const float* __restrict__ Wproj,
                            half_t* __restrict__ WeH, half_t* __restrict__ WpH,
                            float* __restrict__ Wh32) {
  int t = blockIdx.x * blockDim.x + threadIdx.x;
  if (t < 128 * 288) {
    int n = t / 288, kp = t % 288;
    int k = kp < 160 ? kp : kp + 128;
    WeH[n * 288 + kp] = (half_t)We[n * 416 + k];
  }
  if (t < 128 * 128) {
    int n = t >> 7, k = t & 127;
    WpH[t] = (half_t)Wproj[t];
    Wh32[k * 128 + n] = We[n * 416 + 160 + k];
  }
}

// ---------------- knn: exact top-48 ordered by float64 (D, idx) ----------------
__global__ __launch_bounds__(256) void knn_kernel(const float* __restrict__ X,
                                                  int* __restrict__ out_idx,
                                                  float* __restrict__ out_D) {
  __shared__ unsigned hist[1024];
  __shared__ unsigned psum[256];
  __shared__ double candD[256];
  __shared__ int candJ[256];
  __shared__ unsigned cnt;
  __shared__ int bstar_s;
  const int i = blockIdx.x;
  const int tid = threadIdx.x;
  const float xi = X[i * 3 + 0], yi = X[i * 3 + 1], zi = X[i * 3 + 2];
  for (int b = tid; b < 1024; b += 256) hist[b] = 0u;
  if (tid == 0) cnt = 0u;
  __syncthreads();
  // pass 1: fp32 distances -> histogram
  for (int j = tid; j < LRES; j += 256) {
    float dx = X[j * 3 + 0] - xi;
    float dy = X[j * 3 + 1] - yi;
    float dz = X[j * 3 + 2] - zi;
    float D = sqrtf(dx * dx + dy * dy + dz * dz + 1e-6f);
    int b = (int)(D * 4.0f); if (b > 1023) b = 1023;
    atomicAdd(&hist[b], 1u);
  }
  __syncthreads();
  unsigned s4 = hist[tid * 4 + 0] + hist[tid * 4 + 1] + hist[tid * 4 + 2] + hist[tid * 4 + 3];
  psum[tid] = s4;
  __syncthreads();
  if (tid == 0) {
    unsigned run = 0; int g = 0;
    while (g < 255 && run + psum[g] < KNB) { run += psum[g]; ++g; }
    int b = g * 4;
    while (b < g * 4 + 3 && run + hist[b] < KNB) { run += hist[b]; ++b; }
    bstar_s = b;
  }
  __syncthreads();
  int bthr = bstar_s + 1; if (bthr > 1023) bthr = 1023;  // +1 bin slack covers fp32 vs fp64
  const double xid = (double)xi, yid = (double)yi, zid = (double)zi;
  // pass 2: recompute, collect candidates with exact fp64 key
  for (int j = tid; j < LRES; j += 256) {
    float dx = X[j * 3 + 0] - xi;
    float dy = X[j * 3 + 1] - yi;
    float dz = X[j * 3 + 2] - zi;
    float D = sqrtf(dx * dx + dy * dy + dz * dz + 1e-6f);
    int b = (int)(D * 4.0f); if (b > 1023) b = 1023;
    if (b <= bthr) {
      unsigned p = atomicAdd(&cnt, 1u);
      if (p < 256u) {
        double ddx = (double)X[j * 3 + 0] - xid;
        double ddy = (double)X[j * 3 + 1] - yid;
        double ddz = (double)X[j * 3 + 2] - zid;
        candD[p] = sqrt(ddx * ddx + ddy * ddy + ddz * ddz + 1e-6);
        candJ[p] = j;
      }
    }
  }
  __syncthreads();
  unsigned n = cnt;
  if (tid >= (int)n) { candD[tid] = INFINITY; candJ[tid] = 0x7FFFFFFF; }
  __syncthreads();
  // bitonic sort 256 (D,idx) ascending lexicographic == jax top_k order
  for (unsigned size = 2; size <= 256; size <<= 1) {
    for (unsigned stride = size >> 1; stride > 0; stride >>= 1) {
      unsigned partner = (unsigned)tid ^ stride;
      if (partner > (unsigned)tid) {
        double da = candD[tid], db = candD[partner];
        int ja = candJ[tid], jb = candJ[partner];
        bool agtb = (da > db) || (da == db && ja > jb);
        bool asc = ((tid & size) == 0);
        if (agtb == asc) {
          candD[tid] = db; candJ[tid] = jb;
          candD[partner] = da; candJ[partner] = ja;
        }
      }
      __syncthreads();
    }
  }
  if (tid < KNB) {
    out_idx[(size_t)i * KNB + tid] = candJ[tid];
    out_D[(size_t)i * KNB + tid] = (float)candD[tid];
  }
}

// ---------------- edge kernel: features + f16-MFMA GEMMs + LN, one block per residue ----------------
__global__ __launch_bounds__(256, 4) void edge_kernel(
    const float* __restrict__ X, const float* __restrict__ node_h,
    const float* __restrict__ f_node, const float* __restrict__ Wpos,
    const float* __restrict__ bpos, const float* __restrict__ ln_scale,
    const float* __restrict__ ln_bias, const float* __restrict__ bproj,
    const int* __restrict__ aatype, const int* __restrict__ residue_index,
    const int* __restrict__ ws_idx, const float* __restrict__ ws_D,
    const half_t* __restrict__ WeH, const half_t* __restrict__ WpH,
    const float* __restrict__ Wh32, float* __restrict__ out) {
  __shared__ __align__(16) half_t Ald[48 * ASTR];   // 28416 B: e_in^T rows=edges, f16
  __shared__ float poolW[1056];                     // WposL; aliased by redS/mean/rstd after P2
  __shared__ float geomL[48 * 8];
  __shared__ float hbias[128], lnsL[128], lnbL[128], bprojL[128], hiL[128];
  __shared__ float bposL[16], DkL[48];
  __shared__ int jL[48], pidxL[48], aaL[48];

  float* redS  = poolW;          // [48][8] (sum,sq per wave) - after GEMM1 only
  float* meanL = poolW + 384;
  float* rstdL = poolW + 432;

  const int i = blockIdx.x;
  const int tid = threadIdx.x;
  const int w = tid >> 6;            // wave 0..3
  const int lane = tid & 63;
  const int lm = lane & 15;
  const int quad = lane >> 4;
  const int quad8 = quad * 8;
  const int n0 = w * 32 + lm;        // this wave's base output column

  // ---- P0: small loads + per-edge scalars ----
  if (tid < 128) {
    lnsL[tid] = ln_scale[tid];
    lnbL[tid] = ln_bias[tid];
    bprojL[tid] = bproj[tid];
    hiL[tid] = node_h[(size_t)i * 128 + tid];
  }
  for (int t = tid; t < 1056; t += 256) poolW[t] = Wpos[t];
  if (tid < 16) bposL[tid] = bpos[tid];
  const float xi = X[i * 3 + 0], yi = X[i * 3 + 1], zi = X[i * 3 + 2];
  if (tid < KNB) {
    int e = tid;
    int j = ws_idx[(size_t)i * KNB + e];
    float Dk = ws_D[(size_t)i * KNB + e];
    jL[e] = j; DkL[e] = Dk;
    float xj = X[j * 3 + 0], yj = X[j * 3 + 1], zj = X[j * 3 + 2];
    float inv = 1.0f / (Dk + 1e-6f);
    geomL[e * 8 + 0] = Dk / 10.0f;
    geomL[e * 8 + 1] = 1.0f / (1.0f + Dk);
    geomL[e * 8 + 2] = expf(-Dk);
    geomL[e * 8 + 3] = sinf(Dk);
    geomL[e * 8 + 4] = cosf(Dk);
    geomL[e * 8 + 5] = (xj - xi) * inv;
    geomL[e * 8 + 6] = (yj - yi) * inv;
    geomL[e * 8 + 7] = (zj - zi) * inv;
    int off = residue_index[j] - residue_index[i] + 8;
    off = off < 0 ? 0 : (off > 15 ? 15 : off);
    pidxL[e] = off;
    aaL[e] = aatype[j];
  }
  __syncthreads();

  // ---- P1: rbf (f16, cols 144..159) + gathers f_node->0..127, node_h[j]->160..287 ----
  for (int t = tid; t < KNB * 16; t += 256) {
    int e = t >> 4, m = t & 15;
    float z = (DkL[e] - (2.0f + (float)m * (20.0f / 15.0f))) * 0.8f;
    Ald[e * ASTR + 144 + m] = (half_t)expf(-z * z);
  }
  {
    union H2 { unsigned u; half_t h[2]; };
    int c2 = tid & 63;              // column pair
#pragma unroll
    for (int it = 0; it < 12; ++it) {
      int e = it * 4 + w;
      size_t j = (size_t)jL[e];
      float2 f2 = *(const float2*)(f_node + j * 128 + 2 * c2);
      float2 h2 = *(const float2*)(node_h + j * 128 + 2 * c2);
      H2 pf, ph;
      pf.h[0] = (half_t)f2.x; pf.h[1] = (half_t)f2.y;
      ph.h[0] = (half_t)h2.x; ph.h[1] = (half_t)h2.y;
      half_t* row = Ald + e * ASTR;
      *(unsigned*)(row + 2 * c2) = pf.u;
      *(unsigned*)(row + 160 + 2 * c2) = ph.u;
    }
  }
  __syncthreads();

  // ---- P2: e_pos (cols 128..143) + fp32 h_i bias GEMV ----
  for (int t = tid; t < KNB * 16; t += 256) {
    int e = t >> 4, p = t & 15;
    const float* wp = poolW + p * 66;
    const half_t* arow = Ald + e * ASTR;
    float s = bposL[p] + wp[pidxL[e]] + wp[40 + aaL[e]];
#pragma unroll
    for (int m = 0; m < 16; ++m) s = fmaf((float)arow[144 + m], wp[16 + m], s);
#pragma unroll
    for (int g = 0; g < 8; ++g) s = fmaf(geomL[e * 8 + g], wp[32 + g], s);
    Ald[e * ASTR + 128 + p] = (half_t)s;
  }
  if (tid < 128) {
    float s = 0.f;
#pragma unroll 8
    for (int cc = 0; cc < 128; ++cc) s = fmaf(Wh32[cc * 128 + tid], hiL[cc], s);
    hbias[tid] = s;
  }
  __syncthreads();

  // ---- GEMM1: e = A(48x288) @ WeH^T via f16 MFMA; wave w owns cols [w*32, w*32+32) ----
  f4 acc[3][2] = {};
#pragma unroll
  for (int ks = 0; ks < 9; ++ks) {
    int k0 = ks * 32;
    half8 b0 = *(const half8*)(WeH + (size_t)n0 * 288 + k0 + quad8);
    half8 b1 = *(const half8*)(WeH + (size_t)(n0 + 16) * 288 + k0 + quad8);
#pragma unroll
    for (int mt = 0; mt < 3; ++mt) {
      half8 a = *(const half8*)(Ald + (mt * 16 + lm) * ASTR + k0 + quad8);
      acc[mt][0] = __builtin_amdgcn_mfma_f32_16x16x32_f16(a, b0, acc[mt][0], 0, 0, 0);
      acc[mt][1] = __builtin_amdgcn_mfma_f32_16x16x32_f16(a, b1, acc[mt][1], 0, 0, 0);
    }
  }

  // ---- add h_i bias; LN partials (sum over this wave's 32 cols via shfl) ----
  {
    float hb0 = hbias[n0], hb1 = hbias[n0 + 16];
#pragma unroll
    for (int mt = 0; mt < 3; ++mt)
#pragma unroll
      for (int r = 0; r < 4; ++r) { acc[mt][0][r] += hb0; acc[mt][1][r] += hb1; }
  }
#pragma unroll
  for (int mt = 0; mt < 3; ++mt)
#pragma unroll
    for (int r = 0; r < 4; ++r) {
      float e0 = acc[mt][0][r], e1 = acc[mt][1][r];
      float sv = e0 + e1;
      float qv = e0 * e0 + e1 * e1;
#pragma unroll
      for (int m = 1; m < 16; m <<= 1) {
        sv += __shfl_xor(sv, m, 16);
        qv += __shfl_xor(qv, m, 16);
      }
      if (lm == 0) {
        int row = mt * 16 + quad * 4 + r;
        redS[row * 8 + w * 2 + 0] = sv;
        redS[row * 8 + w * 2 + 1] = qv;
      }
    }
  __syncthreads();
  if (tid < KNB) {
    float s = redS[tid * 8 + 0] + redS[tid * 8 + 2] + redS[tid * 8 + 4] + redS[tid * 8 + 6];
    float q = redS[tid * 8 + 1] + redS[tid * 8 + 3] + redS[tid * 8 + 5] + redS[tid * 8 + 7];
    float m = s * (1.0f / 128.0f);
    float var = q * (1.0f / 128.0f) - m * m;
    meanL[tid] = m;
    rstdL[tid] = rsqrtf(var + 1e-5f);
  }
  __syncthreads();

  // ---- eln -> f16 back into Ald rows (cols 0..127), then GEMM2 ----
#pragma unroll
  for (int mt = 0; mt < 3; ++mt)
#pragma unroll
    for (int nt = 0; nt < 2; ++nt) {
      int n = n0 + nt * 16;
      float ls = lnsL[n], lb = lnbL[n];
#pragma unroll
      for (int r = 0; r < 4; ++r) {
        int m = mt * 16 + quad * 4 + r;
        float e = (acc[mt][nt][r] - meanL[m]) * rstdL[m] * ls + lb;
        Ald[m * ASTR + n] = (half_t)e;
      }
    }
  __syncthreads();

  f4 acc2[3][2] = {};
#pragma unroll
  for (int ks = 0; ks < 4; ++ks) {
    int k0 = ks * 32;
    half8 b0 = *(const half8*)(WpH + (size_t)n0 * 128 + k0 + quad8);
    half8 b1 = *(const half8*)(WpH + (size_t)(n0 + 16) * 128 + k0 + quad8);
#pragma unroll
    for (int mt = 0; mt < 3; ++mt) {
      half8 a = *(const half8*)(Ald + (mt * 16 + lm) * ASTR + k0 + quad8);
      acc2[mt][0] = __builtin_amdgcn_mfma_f32_16x16x32_f16(a, b0, acc2[mt][0], 0, 0, 0);
      acc2[mt][1] = __builtin_amdgcn_mfma_f32_16x16x32_f16(a, b1, acc2[mt][1], 0, 0, 0);
    }
  }

  // ---- epilogue ----
#pragma unroll
  for (int mt = 0; mt < 3; ++mt)
#pragma unroll
    for (int nt = 0; nt < 2; ++nt) {
      int n = n0 + nt * 16;
      float bp = bprojL[n];
#pragma unroll
      for (int r = 0; r < 4; ++r) {
        int m = mt * 16 + quad * 4 + r;
        out[((size_t)i * KNB + m) * 128 + n] = acc2[mt][nt][r] + bp;
      }
    }
}

extern "C" void kernel_launch(void* const* d_in, const int* in_sizes, int n_in,
                              void* d_out, int out_size, void* d_ws, size_t ws_size,
                              hipStream_t stream) {
  const float* X        = (const float*)d_in[0];
  const float* node_h   = (const float*)d_in[1];
  const float* f_node   = (const float*)d_in[2];
  const float* Wpos     = (const float*)d_in[3];
  const float* bpos     = (const float*)d_in[4];
  const float* We       = (const float*)d_in[5];
  const float* ln_scale = (const float*)d_in[6];
  const float* ln_bias  = (const float*)d_in[7];
  const float* Wproj    = (const float*)d_in[8];
  const float* bproj    = (const float*)d_in[9];
  const int*   aatype   = (const int*)d_in[10];
  const int*   residue_index = (const int*)d_in[11];
  float* out = (float*)d_out;

  char* ws = (char*)d_ws;
  int*    ws_idx = (int*)ws;                     // 1.5 MB
  float*  ws_D   = (float*)(ws + 1572864);       // 1.5 MB
  half_t* WeH    = (half_t*)(ws + 3145728);      // 73728 B
  half_t* WpH    = (half_t*)(ws + 3219456);      // 32768 B
  float*  Wh32   = (float*)(ws + 3252224);       // 65536 B

  prep_kernel<<<144, 256, 0, stream>>>(We, Wproj, WeH, WpH, Wh32);
  knn_kernel<<<LRES, 256, 0, stream>>>(X, ws_idx, ws_D);
  edge_kernel<<<LRES, 256, 0, stream>>>(X, node_h, f_node, Wpos, bpos, ln_scale,
                                        ln_bias, bproj, aatype, residue_index,
                                        ws_idx, ws_D, WeH, WpH, Wh32, out);
}